// Round 8
// baseline (131.669 us; speedup 1.0000x reference)
//
#include <hip/hip_runtime.h>
#include <math.h>

// out = Re(FFT2(x, axes=(1,2))), x: [B=4, S=8192, D=768] f32, x REAL.
// Hermitian: out[(S-ks)%S][(D-kd)%D] = out[ks][kd]. Compute only ks%64 <= 32.
// Four-step along S (8192 = 128 x 64), k = k2 + 64*k1, keep k2 = 0..32:
//   s1: packed-real register FFT-64 (8x8) over n2; ONE block = full 768-col
//       row set for its n1 -> 3KB contiguous reads, 6KB contiguous writes.
//   s2: pre-twiddle W8192^{n1*k2}, radix-4+2 FFT-128 over n1, in place
//   d : radix-4 FFT-768 (3x256) along d, Re -> direct row + mirror row, coalesced
// Compact plane rows: rc = bb*4224 + n1*33 + k2.

#define S_LEN 8192
#define D_LEN 768
#define NK2 33
#define ROWS_PB (128 * NK2)            // 4224 rows per batch
#define TWO_PI 6.28318530717958647692f

__device__ __forceinline__ int dr128(int p) {  // stages [4,4,4,2]
    return ((p & 1) << 6) | (((p >> 1) & 3) << 4) | (((p >> 3) & 3) << 2) | (p >> 5);
}
__device__ __forceinline__ int dr256(int p) {  // base-4 digit reverse, 4 digits
    return ((p & 3) << 6) | (((p >> 2) & 3) << 4) | (((p >> 4) & 3) << 2) | (p >> 6);
}
__device__ __forceinline__ int F2(int pos) {   // d-kernel float2 index of row-pair 0
    return 4 * pos + (pos >> 2);
}

__device__ __forceinline__ float2 cadd(float2 a, float2 b) {
    return make_float2(a.x + b.x, a.y + b.y);
}
__device__ __forceinline__ float2 csub(float2 a, float2 b) {
    return make_float2(a.x - b.x, a.y - b.y);
}
__device__ __forceinline__ float2 cmulf(float2 a, float2 b) {
    return make_float2(a.x * b.x - a.y * b.y, a.x * b.y + a.y * b.x);
}
__device__ __forceinline__ float2 mul_mi(float2 a) {   // a * (-i)
    return make_float2(a.y, -a.x);
}

// 8-point DIF FFT, natural-in natural-out, constant twiddles, all registers.
__device__ __forceinline__ void fft8(const float2* a, float2* X) {
    const float R2 = 0.70710678118654752440f;
    float2 u0 = cadd(a[0], a[4]), v0 = csub(a[0], a[4]);
    float2 u1 = cadd(a[1], a[5]), v1 = csub(a[1], a[5]);
    float2 u2 = cadd(a[2], a[6]), v2 = csub(a[2], a[6]);
    float2 u3 = cadd(a[3], a[7]), v3 = csub(a[3], a[7]);
    v1 = make_float2(R2 * (v1.x + v1.y), R2 * (v1.y - v1.x));   // *W8^1
    v2 = mul_mi(v2);                                            // *W8^2
    v3 = make_float2(R2 * (v3.y - v3.x), -R2 * (v3.x + v3.y));  // *W8^3
    float2 e0 = cadd(u0, u2), o0 = csub(u0, u2);
    float2 e1 = cadd(u1, u3), o1 = mul_mi(csub(u1, u3));
    X[0] = cadd(e0, e1); X[4] = csub(e0, e1);
    X[2] = cadd(o0, o1); X[6] = csub(o0, o1);
    float2 f0 = cadd(v0, v2), p0 = csub(v0, v2);
    float2 f1 = cadd(v1, v3), p1 = mul_mi(csub(v1, v3));
    X[1] = cadd(f0, f1); X[5] = csub(f0, f1);
    X[3] = cadd(p0, p1); X[7] = csub(p0, p1);
}

// radix-4 DIF butterfly on separate re/im LDS planes, b32 [pos*32 + col] layout
#define BFLY4(zre, zim, a0, a1, a2, a3, w1, w2, w3)                            \
    {                                                                          \
        float ar = zre[a0], ai = zim[a0], br = zre[a1], bi = zim[a1];          \
        float cr = zre[a2], ci = zim[a2], er = zre[a3], ei = zim[a3];          \
        float t0r = ar + cr, t0i = ai + ci, t1r = ar - cr, t1i = ai - ci;      \
        float t2r = br + er, t2i = bi + ei, t3r = br - er, t3i = bi - ei;      \
        zre[a0] = t0r + t2r; zim[a0] = t0i + t2i;                              \
        float B1r = t1r + t3i, B1i = t1i - t3r;                                \
        zre[a1] = B1r * w1.x - B1i * w1.y; zim[a1] = B1r * w1.y + B1i * w1.x;  \
        float B2r = t0r - t2r, B2i = t0i - t2i;                                \
        zre[a2] = B2r * w2.x - B2i * w2.y; zim[a2] = B2r * w2.y + B2i * w2.x;  \
        float B3r = t1r - t3i, B3i = t1i + t3r;                                \
        zre[a3] = B3r * w3.x - B3i * w3.y; zim[a3] = B3r * w3.y + B3i * w3.x;  \
    }

// ---------------- s1: packed-real register FFT-64 (8x8) over n2 ----------------
// n2 = na + 8*nb; k = kb + 8*ka. Block = (bb, n1): ALL 768 cols, 64 rows.
// 1024 threads = 8 na x 128 c. 3 col-groups (256 real = 128 packed each)
// time-share one 64x129 LDS buffer. Reads: 64 rows x 3KB contiguous.
#define ZSTR2 129
__global__ __launch_bounds__(1024) void fft_s1_kernel(const float* __restrict__ x,
                                                      float2* __restrict__ Y,
                                                      int b0) {
    __shared__ float2 Z[64 * ZSTR2];               // 66,048 B
    const int bid = blockIdx.x;
    const int n1 = bid % 128;
    const int bb = bid / 128;
    const int b = b0 + bb;
    const int t = threadIdx.x;
    const int c = t & 127;
    const int na = t >> 7;                         // 0..7

    // 24 loads up-front: groups m=0,1,2 x nb2=0..7; 3KB contiguous per row.
    float2 v0[8], v1[8], v2g[8];
    {
        const size_t rowstep = (size_t)1024 * D_LEN;
        const size_t xbase =
            ((size_t)b * S_LEN + n1 + 128 * na) * D_LEN + 2 * c;
        #pragma unroll
        for (int nb2 = 0; nb2 < 8; ++nb2)
            v0[nb2] = *(const float2*)(x + xbase + (size_t)nb2 * rowstep);
        #pragma unroll
        for (int nb2 = 0; nb2 < 8; ++nb2)
            v1[nb2] = *(const float2*)(x + xbase + (size_t)nb2 * rowstep + 256);
        #pragma unroll
        for (int nb2 = 0; nb2 < 8; ++nb2)
            v2g[nb2] = *(const float2*)(x + xbase + (size_t)nb2 * rowstep + 512);
    }

    // twiddle chain W64^{na*k}, shared across the 3 groups
    float2 wk1, wk2, wk3, wk4, wk5, wk6, wk7;
    {
        float s_, co;
        sincosf(-TWO_PI * (float)na / 64.0f, &s_, &co);
        wk1 = make_float2(co, s_);
        wk2 = cmulf(wk1, wk1); wk3 = cmulf(wk2, wk1); wk4 = cmulf(wk3, wk1);
        wk5 = cmulf(wk4, wk1); wk6 = cmulf(wk5, wk1); wk7 = cmulf(wk6, wk1);
    }

    const size_t rcb = (size_t)bb * ROWS_PB + (size_t)n1 * NK2;

    #pragma unroll
    for (int m = 0; m < 3; ++m) {
        // inner FFT8 over nb + twiddle
        float2 g[8];
        if (m == 0) fft8(v0, g);
        else if (m == 1) fft8(v1, g);
        else fft8(v2g, g);
        g[1] = cmulf(g[1], wk1); g[2] = cmulf(g[2], wk2);
        g[3] = cmulf(g[3], wk3); g[4] = cmulf(g[4], wk4);
        g[5] = cmulf(g[5], wk5); g[6] = cmulf(g[6], wk6);
        g[7] = cmulf(g[7], wk7);

        if (m > 0) __syncthreads();                // prev group's reads done
        #pragma unroll
        for (int k = 0; k < 8; ++k) Z[(8 * k + na) * ZSTR2 + c] = g[k];
        __syncthreads();

        // outer FFT8 over na
        float2 h[8], r[8];
        #pragma unroll
        for (int j = 0; j < 8; ++j) h[j] = Z[(8 * na + j) * ZSTR2 + c];
        fft8(h, r);
        __syncthreads();
        #pragma unroll
        for (int ka = 0; ka < 8; ++ka) Z[(na + 8 * ka) * ZSTR2 + c] = r[ka];
        __syncthreads();

        // Hermitian unpack (packed-real col pair 2c,2c+1) + 1KB-per-wave stores
        #pragma unroll
        for (int it = 0; it < 5; ++it) {
            const int k2 = na + 8 * it;
            if (k2 <= 32) {
                const float2 z1 = Z[k2 * ZSTR2 + c];
                const float2 z2 = Z[((64 - k2) & 63) * ZSTR2 + c];
                const float Ar = 0.5f * (z1.x + z2.x), Ai = 0.5f * (z1.y - z2.y);
                const float Br = 0.5f * (z1.y + z2.y), Bi = -0.5f * (z1.x - z2.x);
                const size_t idx = (rcb + k2) * D_LEN + m * 256 + 2 * c;
                *(float4*)(Y + idx) = make_float4(Ar, Ai, Br, Bi);
            }
        }
    }
}

// ---------------- s2: pre-twiddle + radix-4+2 FFT-128 over n1 ----------------
__global__ __launch_bounds__(256) void fft_s2_kernel(float2* __restrict__ Y) {
    __shared__ float sre[128 * 32], sim[128 * 32];
    __shared__ float2 pt[128];     // W_8192^{n1*k2}
    __shared__ float2 t128[128];
    const int bid = blockIdx.x;
    const int dt = bid % 24;
    const int k2 = (bid / 24) % NK2;
    const int bb = bid / (24 * NK2);
    const int t = threadIdx.x;
    const int d = t & 31;
    const int g = t >> 5;

    if (t < 128) {
        float s, co;
        sincosf(-TWO_PI * (float)(t * k2) / 8192.0f, &s, &co);
        pt[t] = make_float2(co, s);
        sincosf(-TWO_PI * (float)t / 128.0f, &s, &co);
        t128[t] = make_float2(co, s);
    }
    __syncthreads();

    const size_t base_rc = (size_t)bb * ROWS_PB + k2;
    const int col = dt * 32 + d;
    for (int j = g; j < 128; j += 8) {
        const float2 v = Y[(base_rc + (size_t)j * NK2) * D_LEN + col];
        const float2 w = pt[j];
        sre[j * 32 + d] = v.x * w.x - v.y * w.y;
        sim[j * 32 + d] = v.x * w.y + v.y * w.x;
    }
    __syncthreads();

    // stage L=128, Q=32
    #pragma unroll
    for (int it = 0; it < 4; ++it) {
        const int p = g + 8 * it;                  // 0..31
        const int a0 = p * 32 + d;
        const float2 w1 = t128[p], w2 = t128[2 * p], w3 = t128[3 * p];
        BFLY4(sre, sim, a0, a0 + 32 * 32, a0 + 64 * 32, a0 + 96 * 32, w1, w2, w3);
    }
    __syncthreads();
    // stage L=32, Q=8
    #pragma unroll
    for (int it = 0; it < 4; ++it) {
        const int i = g + 8 * it;
        const int blk = i >> 3, p = i & 7;
        const int a0 = (blk * 32 + p) * 32 + d;
        const float2 w1 = t128[4 * p], w2 = t128[8 * p], w3 = t128[12 * p];
        BFLY4(sre, sim, a0, a0 + 8 * 32, a0 + 16 * 32, a0 + 24 * 32, w1, w2, w3);
    }
    __syncthreads();
    // stage L=8, Q=2
    #pragma unroll
    for (int it = 0; it < 4; ++it) {
        const int i = g + 8 * it;
        const int blk = i >> 1, p = i & 1;
        const int a0 = (blk * 8 + p) * 32 + d;
        const float2 w1 = t128[16 * p], w2 = t128[32 * p], w3 = t128[48 * p];
        BFLY4(sre, sim, a0, a0 + 2 * 32, a0 + 4 * 32, a0 + 6 * 32, w1, w2, w3);
    }
    __syncthreads();
    // stage L=2 (radix-2, no twiddle)
    #pragma unroll
    for (int it = 0; it < 8; ++it) {
        const int i = g + 8 * it;                  // 0..63
        const int a0 = (2 * i) * 32 + d, a1 = a0 + 32;
        float ar = sre[a0], ai = sim[a0], br = sre[a1], bi = sim[a1];
        sre[a0] = ar + br; sim[a0] = ai + bi;
        sre[a1] = ar - br; sim[a1] = ai - bi;
    }
    __syncthreads();

    for (int j = g; j < 128; j += 8) {
        const int k1 = dr128(j);
        Y[(base_rc + (size_t)k1 * NK2) * D_LEN + col] =
            make_float2(sre[j * 32 + d], sim[j * 32 + d]);
    }
}

// ---------------- d: radix-4 FFT-768 per row + Hermitian mirror ----------------
// LDS: F(pos,row) = 8*pos + 2*(pos>>2) + row; row pair via float2 idx F2(pos)+m.
__global__ __launch_bounds__(256) void fft_d_kernel(const float2* __restrict__ Y,
                                                    float* __restrict__ out,
                                                    int b0) {
    __shared__ float sre[6528], sim[6528];   // 2 x 26112 B
    __shared__ float2 t768[256];             // W768^k; W256^p = t768[3p]
    const int t = threadIdx.x;
    const int rc0 = blockIdx.x * 8;

    {
        float s, co;
        sincosf(-TWO_PI * (float)t / 768.0f, &s, &co);
        t768[t] = make_float2(co, s);
    }

    // load: row rw = t>>5 (0..7), q = t&31; 256B coalesced per wave-row
    {
        const int rw = t >> 5;
        const int q = t & 31;
        const size_t grow = (size_t)(rc0 + rw) * D_LEN;
        #pragma unroll
        for (int jl = 0; jl < 24; ++jl) {
            const int n = q + 32 * jl;
            const float2 v = Y[grow + n];
            const int pos = (n % 3) * 256 + n / 3;
            const int fi = 8 * pos + 2 * (pos >> 2) + rw;
            sre[fi] = v.x;
            sim[fi] = v.y;
        }
    }
    __syncthreads();

    // butterflies: m = t&3 row pair, q2 = t>>2 in 0..63
    const int m = t & 3;
    const int q2 = t >> 2;
    float2* s2re = (float2*)sre;
    float2* s2im = (float2*)sim;

#define BFLY4V(a0, a1, a2, a3, w1, w2, w3)                                      \
    {                                                                           \
        float2 ar = s2re[a0], ai = s2im[a0], br = s2re[a1], bi = s2im[a1];      \
        float2 cr = s2re[a2], ci = s2im[a2], er = s2re[a3], ei = s2im[a3];      \
        float2 t0r = make_float2(ar.x + cr.x, ar.y + cr.y);                     \
        float2 t0i = make_float2(ai.x + ci.x, ai.y + ci.y);                     \
        float2 t1r = make_float2(ar.x - cr.x, ar.y - cr.y);                     \
        float2 t1i = make_float2(ai.x - ci.x, ai.y - ci.y);                     \
        float2 t2r = make_float2(br.x + er.x, br.y + er.y);                     \
        float2 t2i = make_float2(bi.x + ei.x, bi.y + ei.y);                     \
        float2 t3r = make_float2(br.x - er.x, br.y - er.y);                     \
        float2 t3i = make_float2(bi.x - ei.x, bi.y - ei.y);                     \
        s2re[a0] = make_float2(t0r.x + t2r.x, t0r.y + t2r.y);                   \
        s2im[a0] = make_float2(t0i.x + t2i.x, t0i.y + t2i.y);                   \
        float2 B1r = make_float2(t1r.x + t3i.x, t1r.y + t3i.y);                 \
        float2 B1i = make_float2(t1i.x - t3r.x, t1i.y - t3r.y);                 \
        s2re[a1] = make_float2(B1r.x * w1.x - B1i.x * w1.y,                     \
                               B1r.y * w1.x - B1i.y * w1.y);                    \
        s2im[a1] = make_float2(B1r.x * w1.y + B1i.x * w1.x,                     \
                               B1r.y * w1.y + B1i.y * w1.x);                    \
        float2 B2r = make_float2(t0r.x - t2r.x, t0r.y - t2r.y);                 \
        float2 B2i = make_float2(t0i.x - t2i.x, t0i.y - t2i.y);                 \
        s2re[a2] = make_float2(B2r.x * w2.x - B2i.x * w2.y,                     \
                               B2r.y * w2.x - B2i.y * w2.y);                    \
        s2im[a2] = make_float2(B2r.x * w2.y + B2i.x * w2.x,                     \
                               B2r.y * w2.y + B2i.y * w2.x);                    \
        float2 B3r = make_float2(t1r.x - t3i.x, t1r.y - t3i.y);                 \
        float2 B3i = make_float2(t1i.x + t3r.x, t1i.y + t3r.y);                 \
        s2re[a3] = make_float2(B3r.x * w3.x - B3i.x * w3.y,                     \
                               B3r.y * w3.x - B3i.y * w3.y);                    \
        s2im[a3] = make_float2(B3r.x * w3.y + B3i.x * w3.x,                     \
                               B3r.y * w3.y + B3i.y * w3.x);                    \
    }
#define CSQ(w) make_float2((w).x * (w).x - (w).y * (w).y, 2.0f * (w).x * (w).y)
#define CMU(a, b) make_float2((a).x * (b).x - (a).y * (b).y,                    \
                              (a).x * (b).y + (a).y * (b).x)

    // stage L=256, Q=64
    #pragma unroll
    for (int jj = 0; jj < 3; ++jj) {
        const int bf = q2 + 64 * jj;
        const int sub = bf >> 6;
        const int p = bf & 63;
        const int base = sub * 256 + p;
        const float2 w1 = t768[3 * p];
        const float2 w2 = CSQ(w1);
        const float2 w3 = CMU(w1, w2);
        BFLY4V(F2(base) + m, F2(base + 64) + m, F2(base + 128) + m,
               F2(base + 192) + m, w1, w2, w3);
    }
    __syncthreads();
    // stage L=64, Q=16
    #pragma unroll
    for (int jj = 0; jj < 3; ++jj) {
        const int bf = q2 + 64 * jj;
        const int sub = bf >> 6;
        const int i = bf & 63;
        const int blk = i >> 4, p = i & 15;
        const int base = sub * 256 + blk * 64 + p;
        const float2 w1 = t768[12 * p];
        const float2 w2 = CSQ(w1);
        const float2 w3 = CMU(w1, w2);
        BFLY4V(F2(base) + m, F2(base + 16) + m, F2(base + 32) + m,
               F2(base + 48) + m, w1, w2, w3);
    }
    __syncthreads();
    // stage L=16, Q=4
    #pragma unroll
    for (int jj = 0; jj < 3; ++jj) {
        const int bf = q2 + 64 * jj;
        const int sub = bf >> 6;
        const int i = bf & 63;
        const int blk = i >> 2, p = i & 3;
        const int base = sub * 256 + blk * 16 + p;
        const float2 w1 = t768[48 * p];
        const float2 w2 = CSQ(w1);
        const float2 w3 = CMU(w1, w2);
        BFLY4V(F2(base) + m, F2(base + 4) + m, F2(base + 8) + m,
               F2(base + 12) + m, w1, w2, w3);
    }
    __syncthreads();
    // stage L=4, Q=1 (no twiddle)
    {
        const float2 wid = make_float2(1.0f, 0.0f);
        #pragma unroll
        for (int jj = 0; jj < 3; ++jj) {
            const int bf = q2 + 64 * jj;
            const int sub = bf >> 6;
            const int i = bf & 63;
            const int base = sub * 256 + 4 * i;
            BFLY4V(F2(base) + m, F2(base + 1) + m, F2(base + 2) + m,
                   F2(base + 3) + m, wid, wid, wid);
        }
    }
    __syncthreads();

    // decode 8 rows of this block
    size_t obase[8], mbase[8];
    bool domir[8];
    #pragma unroll
    for (int rr = 0; rr < 8; ++rr) {
        const int rc = rc0 + rr;
        const int bb = rc / ROWS_PB;
        const int qq = rc - bb * ROWS_PB;
        const int K1 = qq / NK2;
        const int K2 = qq - K1 * NK2;
        const int srow = 64 * K1 + K2;
        const size_t bs = (size_t)(b0 + bb) * S_LEN;
        obase[rr] = (bs + srow) * D_LEN;
        mbase[rr] = (bs + (S_LEN - srow)) * D_LEN;
        domir[rr] = (K2 >= 1 && K2 <= 31);
    }

    // combine (radix-3): thread handles bin kk = t for all 4 row pairs.
    const float W3r = -0.5f, W3i = -0.86602540378443864676f;
    const int kk = t;
    const int j8 = dr256(kk);
    const int e0 = F2(j8), e1 = F2(256 + j8), e2 = F2(512 + j8);
    const float2 w = t768[kk];
    const float c1 = w.x, s1 = w.y;
    const float c2 = c1 * c1 - s1 * s1, s2_ = 2.0f * c1 * s1;
    const int md0 = (kk == 0) ? 0 : (768 - kk);
    #pragma unroll
    for (int i2 = 0; i2 < 4; ++i2) {
        const float2 u0r = s2re[e0 + i2], u0i = s2im[e0 + i2];
        const float2 u1r = s2re[e1 + i2], u1i = s2im[e1 + i2];
        const float2 u2r = s2re[e2 + i2], u2i = s2im[e2 + i2];
        const float2 v1r = make_float2(u1r.x * c1 - u1i.x * s1, u1r.y * c1 - u1i.y * s1);
        const float2 v1i = make_float2(u1r.x * s1 + u1i.x * c1, u1r.y * s1 + u1i.y * c1);
        const float2 v2r = make_float2(u2r.x * c2 - u2i.x * s2_, u2r.y * c2 - u2i.y * s2_);
        const float2 v2i = make_float2(u2r.x * s2_ + u2i.x * c2, u2r.y * s2_ + u2i.y * c2);
        const float2 y0 = make_float2(u0r.x + v1r.x + v2r.x, u0r.y + v1r.y + v2r.y);
        const float2 y1 = make_float2(
            u0r.x + (v1r.x * W3r - v1i.x * W3i) + (v2r.x * W3r + v2i.x * W3i),
            u0r.y + (v1r.y * W3r - v1i.y * W3i) + (v2r.y * W3r + v2i.y * W3i));
        const float2 y2 = make_float2(
            u0r.x + (v1r.x * W3r + v1i.x * W3i) + (v2r.x * W3r - v2i.x * W3i),
            u0r.y + (v1r.y * W3r + v1i.y * W3i) + (v2r.y * W3r - v2i.y * W3i));
        #pragma unroll
        for (int h = 0; h < 2; ++h) {
            const int rr = 2 * i2 + h;
            const float v0 = h ? y0.y : y0.x;
            const float v1 = h ? y1.y : y1.x;
            const float v2 = h ? y2.y : y2.x;
            out[obase[rr] + kk] = v0;
            out[obase[rr] + 256 + kk] = v1;
            out[obase[rr] + 512 + kk] = v2;
            if (domir[rr]) {
                out[mbase[rr] + md0] = v0;
                out[mbase[rr] + 512 - kk] = v1;
                out[mbase[rr] + 256 - kk] = v2;
            }
        }
    }
#undef BFLY4V
#undef CSQ
#undef CMU
}

extern "C" void kernel_launch(void* const* d_in, const int* in_sizes, int n_in,
                              void* d_out, int out_size, void* d_ws, size_t ws_size,
                              hipStream_t stream) {
    const float* x = (const float*)d_in[0];
    float* out = (float*)d_out;
    float2* Y = (float2*)d_ws;

    const size_t full_plane_bytes = (size_t)4 * ROWS_PB * D_LEN * sizeof(float2);
    const size_t half_plane_bytes = full_plane_bytes / 2;
    int nb;
    if (ws_size >= full_plane_bytes) nb = 4;        // single pass (~104 MB)
    else if (ws_size >= half_plane_bytes) nb = 2;   // two passes (~52 MB)
    else return;

    for (int b0 = 0; b0 < 4; b0 += nb) {
        fft_s1_kernel<<<dim3(nb * 128), dim3(1024), 0, stream>>>(x, Y, b0);
        fft_s2_kernel<<<dim3(nb * NK2 * 24), dim3(256), 0, stream>>>(Y);
        fft_d_kernel<<<dim3(nb * ROWS_PB / 8), dim3(256), 0, stream>>>(Y, out, b0);
    }
}

// Round 9
// 109.485 us; speedup vs baseline: 1.2026x; 1.2026x over previous
//
#include <hip/hip_runtime.h>
#include <math.h>

// out = Re(FFT2(x, axes=(1,2))), x: [B=4, S=8192, D=768] f32, x REAL.
// Hermitian: out[(S-ks)%S][(D-kd)%D] = out[ks][kd]. Compute only ks%64 <= 32.
// Four-step along S (8192 = 128 x 64), k = k2 + 64*k1, keep k2 = 0..32:
//   s1: packed-real register FFT-64 (8x8) over n2 -> Y (bf16 re,im packed)
//   s2: pre-twiddle W8192^{n1*k2}, radix-4+2 FFT-128 over n1, in place (bf16 io)
//   d : radix-4 FFT-768 (3x256) along d, Re -> direct + mirror rows, nt stores
// Y plane: uint Y[rc][768], rc = bb*4224 + n1*33 + k2; elem = bf16(re)|bf16(im)<<16.

#define S_LEN 8192
#define D_LEN 768
#define NK2 33
#define ROWS_PB (128 * NK2)            // 4224 rows per batch
#define TWO_PI 6.28318530717958647692f

__device__ __forceinline__ unsigned bf16_of(float f) {
    unsigned u = __float_as_uint(f);
    return (u + 0x7FFFu + ((u >> 16) & 1u)) >> 16;   // RNE
}
__device__ __forceinline__ unsigned pack_bf2(float re, float im) {
    return bf16_of(re) | (bf16_of(im) << 16);
}
__device__ __forceinline__ float2 unpack_bf2(unsigned p) {
    return make_float2(__uint_as_float((p & 0xFFFFu) << 16),
                       __uint_as_float((p >> 16) << 16));
}

__device__ __forceinline__ int dr128(int p) {  // stages [4,4,4,2]
    return ((p & 1) << 6) | (((p >> 1) & 3) << 4) | (((p >> 3) & 3) << 2) | (p >> 5);
}
__device__ __forceinline__ int dr256(int p) {  // base-4 digit reverse, 4 digits
    return ((p & 3) << 6) | (((p >> 2) & 3) << 4) | (((p >> 4) & 3) << 2) | (p >> 6);
}
__device__ __forceinline__ int F2(int pos) {   // d-kernel float2 index of row-pair 0
    return 4 * pos + (pos >> 2);
}

__device__ __forceinline__ float2 cadd(float2 a, float2 b) {
    return make_float2(a.x + b.x, a.y + b.y);
}
__device__ __forceinline__ float2 csub(float2 a, float2 b) {
    return make_float2(a.x - b.x, a.y - b.y);
}
__device__ __forceinline__ float2 cmulf(float2 a, float2 b) {
    return make_float2(a.x * b.x - a.y * b.y, a.x * b.y + a.y * b.x);
}
__device__ __forceinline__ float2 mul_mi(float2 a) {   // a * (-i)
    return make_float2(a.y, -a.x);
}

// 8-point DIF FFT, natural-in natural-out, constant twiddles, all registers.
__device__ __forceinline__ void fft8(const float2* a, float2* X) {
    const float R2 = 0.70710678118654752440f;
    float2 u0 = cadd(a[0], a[4]), v0 = csub(a[0], a[4]);
    float2 u1 = cadd(a[1], a[5]), v1 = csub(a[1], a[5]);
    float2 u2 = cadd(a[2], a[6]), v2 = csub(a[2], a[6]);
    float2 u3 = cadd(a[3], a[7]), v3 = csub(a[3], a[7]);
    v1 = make_float2(R2 * (v1.x + v1.y), R2 * (v1.y - v1.x));   // *W8^1
    v2 = mul_mi(v2);                                            // *W8^2
    v3 = make_float2(R2 * (v3.y - v3.x), -R2 * (v3.x + v3.y));  // *W8^3
    float2 e0 = cadd(u0, u2), o0 = csub(u0, u2);
    float2 e1 = cadd(u1, u3), o1 = mul_mi(csub(u1, u3));
    X[0] = cadd(e0, e1); X[4] = csub(e0, e1);
    X[2] = cadd(o0, o1); X[6] = csub(o0, o1);
    float2 f0 = cadd(v0, v2), p0 = csub(v0, v2);
    float2 f1 = cadd(v1, v3), p1 = mul_mi(csub(v1, v3));
    X[1] = cadd(f0, f1); X[5] = csub(f0, f1);
    X[3] = cadd(p0, p1); X[7] = csub(p0, p1);
}

// radix-4 DIF butterfly on separate re/im LDS planes, b32 [pos*32 + col] layout
#define BFLY4(zre, zim, a0, a1, a2, a3, w1, w2, w3)                            \
    {                                                                          \
        float ar = zre[a0], ai = zim[a0], br = zre[a1], bi = zim[a1];          \
        float cr = zre[a2], ci = zim[a2], er = zre[a3], ei = zim[a3];          \
        float t0r = ar + cr, t0i = ai + ci, t1r = ar - cr, t1i = ai - ci;      \
        float t2r = br + er, t2i = bi + ei, t3r = br - er, t3i = bi - ei;      \
        zre[a0] = t0r + t2r; zim[a0] = t0i + t2i;                              \
        float B1r = t1r + t3i, B1i = t1i - t3r;                                \
        zre[a1] = B1r * w1.x - B1i * w1.y; zim[a1] = B1r * w1.y + B1i * w1.x;  \
        float B2r = t0r - t2r, B2i = t0i - t2i;                                \
        zre[a2] = B2r * w2.x - B2i * w2.y; zim[a2] = B2r * w2.y + B2i * w2.x;  \
        float B3r = t1r - t3i, B3i = t1i + t3r;                                \
        zre[a3] = B3r * w3.x - B3i * w3.y; zim[a3] = B3r * w3.y + B3i * w3.x;  \
    }

// ---------------- s1: packed-real register FFT-64 (8x8) over n2 ----------------
// Block = (bb, n1): all 768 cols, 64 rows. 1024 threads = 8 na x 128 c.
#define ZSTR2 129
__global__ __launch_bounds__(1024) void fft_s1_kernel(const float* __restrict__ x,
                                                      unsigned* __restrict__ Yu,
                                                      int b0) {
    __shared__ float2 Z[64 * ZSTR2];               // 66,048 B
    const int bid = blockIdx.x;
    const int n1 = bid % 128;
    const int bb = bid / 128;
    const int b = b0 + bb;
    const int t = threadIdx.x;
    const int c = t & 127;
    const int na = t >> 7;                         // 0..7

    // 24 loads up-front: groups m=0,1,2 x nb2=0..7; 3KB contiguous per row.
    float2 v0[8], v1[8], v2g[8];
    {
        const size_t rowstep = (size_t)1024 * D_LEN;
        const size_t xbase =
            ((size_t)b * S_LEN + n1 + 128 * na) * D_LEN + 2 * c;
        #pragma unroll
        for (int nb2 = 0; nb2 < 8; ++nb2)
            v0[nb2] = *(const float2*)(x + xbase + (size_t)nb2 * rowstep);
        #pragma unroll
        for (int nb2 = 0; nb2 < 8; ++nb2)
            v1[nb2] = *(const float2*)(x + xbase + (size_t)nb2 * rowstep + 256);
        #pragma unroll
        for (int nb2 = 0; nb2 < 8; ++nb2)
            v2g[nb2] = *(const float2*)(x + xbase + (size_t)nb2 * rowstep + 512);
    }

    // twiddle chain W64^{na*k}, shared across the 3 groups
    float2 wk1, wk2, wk3, wk4, wk5, wk6, wk7;
    {
        float s_, co;
        sincosf(-TWO_PI * (float)na / 64.0f, &s_, &co);
        wk1 = make_float2(co, s_);
        wk2 = cmulf(wk1, wk1); wk3 = cmulf(wk2, wk1); wk4 = cmulf(wk3, wk1);
        wk5 = cmulf(wk4, wk1); wk6 = cmulf(wk5, wk1); wk7 = cmulf(wk6, wk1);
    }

    const size_t rcb = (size_t)bb * ROWS_PB + (size_t)n1 * NK2;

    #pragma unroll
    for (int m = 0; m < 3; ++m) {
        float2 g[8];
        if (m == 0) fft8(v0, g);
        else if (m == 1) fft8(v1, g);
        else fft8(v2g, g);
        g[1] = cmulf(g[1], wk1); g[2] = cmulf(g[2], wk2);
        g[3] = cmulf(g[3], wk3); g[4] = cmulf(g[4], wk4);
        g[5] = cmulf(g[5], wk5); g[6] = cmulf(g[6], wk6);
        g[7] = cmulf(g[7], wk7);

        if (m > 0) __syncthreads();
        #pragma unroll
        for (int k = 0; k < 8; ++k) Z[(8 * k + na) * ZSTR2 + c] = g[k];
        __syncthreads();

        float2 h[8], r[8];
        #pragma unroll
        for (int j = 0; j < 8; ++j) h[j] = Z[(8 * na + j) * ZSTR2 + c];
        fft8(h, r);
        __syncthreads();
        #pragma unroll
        for (int ka = 0; ka < 8; ++ka) Z[(na + 8 * ka) * ZSTR2 + c] = r[ka];
        __syncthreads();

        // Hermitian unpack + bf16 pack + store (8B per thread, coalesced)
        #pragma unroll
        for (int it = 0; it < 5; ++it) {
            const int k2 = na + 8 * it;
            if (k2 <= 32) {
                const float2 z1 = Z[k2 * ZSTR2 + c];
                const float2 z2 = Z[((64 - k2) & 63) * ZSTR2 + c];
                const float Ar = 0.5f * (z1.x + z2.x), Ai = 0.5f * (z1.y - z2.y);
                const float Br = 0.5f * (z1.y + z2.y), Bi = -0.5f * (z1.x - z2.x);
                const size_t idx = (rcb + k2) * D_LEN + m * 256 + 2 * c;
                *(uint2*)(Yu + idx) = make_uint2(pack_bf2(Ar, Ai), pack_bf2(Br, Bi));
            }
        }
    }
}

// ---------------- s2: pre-twiddle + radix-4+2 FFT-128 over n1 ----------------
__global__ __launch_bounds__(256) void fft_s2_kernel(unsigned* __restrict__ Yu) {
    __shared__ float sre[128 * 32], sim[128 * 32];
    __shared__ float2 pt[128];     // W_8192^{n1*k2}
    __shared__ float2 t128[128];
    const int bid = blockIdx.x;
    const int dt = bid % 24;
    const int k2 = (bid / 24) % NK2;
    const int bb = bid / (24 * NK2);
    const int t = threadIdx.x;
    const int d = t & 31;
    const int g = t >> 5;

    if (t < 128) {
        float s, co;
        sincosf(-TWO_PI * (float)(t * k2) / 8192.0f, &s, &co);
        pt[t] = make_float2(co, s);
        sincosf(-TWO_PI * (float)t / 128.0f, &s, &co);
        t128[t] = make_float2(co, s);
    }
    __syncthreads();

    const size_t base_rc = (size_t)bb * ROWS_PB + k2;
    const int col = dt * 32 + d;
    for (int j = g; j < 128; j += 8) {
        const float2 v = unpack_bf2(Yu[(base_rc + (size_t)j * NK2) * D_LEN + col]);
        const float2 w = pt[j];
        sre[j * 32 + d] = v.x * w.x - v.y * w.y;
        sim[j * 32 + d] = v.x * w.y + v.y * w.x;
    }
    __syncthreads();

    // stage L=128, Q=32
    #pragma unroll
    for (int it = 0; it < 4; ++it) {
        const int p = g + 8 * it;                  // 0..31
        const int a0 = p * 32 + d;
        const float2 w1 = t128[p], w2 = t128[2 * p], w3 = t128[3 * p];
        BFLY4(sre, sim, a0, a0 + 32 * 32, a0 + 64 * 32, a0 + 96 * 32, w1, w2, w3);
    }
    __syncthreads();
    // stage L=32, Q=8
    #pragma unroll
    for (int it = 0; it < 4; ++it) {
        const int i = g + 8 * it;
        const int blk = i >> 3, p = i & 7;
        const int a0 = (blk * 32 + p) * 32 + d;
        const float2 w1 = t128[4 * p], w2 = t128[8 * p], w3 = t128[12 * p];
        BFLY4(sre, sim, a0, a0 + 8 * 32, a0 + 16 * 32, a0 + 24 * 32, w1, w2, w3);
    }
    __syncthreads();
    // stage L=8, Q=2
    #pragma unroll
    for (int it = 0; it < 4; ++it) {
        const int i = g + 8 * it;
        const int blk = i >> 1, p = i & 1;
        const int a0 = (blk * 8 + p) * 32 + d;
        const float2 w1 = t128[16 * p], w2 = t128[32 * p], w3 = t128[48 * p];
        BFLY4(sre, sim, a0, a0 + 2 * 32, a0 + 4 * 32, a0 + 6 * 32, w1, w2, w3);
    }
    __syncthreads();
    // stage L=2 (radix-2, no twiddle)
    #pragma unroll
    for (int it = 0; it < 8; ++it) {
        const int i = g + 8 * it;                  // 0..63
        const int a0 = (2 * i) * 32 + d, a1 = a0 + 32;
        float ar = sre[a0], ai = sim[a0], br = sre[a1], bi = sim[a1];
        sre[a0] = ar + br; sim[a0] = ai + bi;
        sre[a1] = ar - br; sim[a1] = ai - bi;
    }
    __syncthreads();

    for (int j = g; j < 128; j += 8) {
        const int k1 = dr128(j);
        Yu[(base_rc + (size_t)k1 * NK2) * D_LEN + col] =
            pack_bf2(sre[j * 32 + d], sim[j * 32 + d]);
    }
}

// ---------------- d: radix-4 FFT-768 per row + Hermitian mirror ----------------
// LDS: F(pos,row) = 8*pos + 2*(pos>>2) + row; row pair via float2 idx F2(pos)+m.
__global__ __launch_bounds__(256) void fft_d_kernel(const unsigned* __restrict__ Yu,
                                                    float* __restrict__ out,
                                                    int b0) {
    __shared__ float sre[6528], sim[6528];   // 2 x 26112 B
    __shared__ float2 t768[256];             // W768^k; W256^p = t768[3p]
    const int t = threadIdx.x;
    const int rc0 = blockIdx.x * 8;

    {
        float s, co;
        sincosf(-TWO_PI * (float)t / 768.0f, &s, &co);
        t768[t] = make_float2(co, s);
    }

    // load: row rw = t>>5 (0..7), q = t&31; 128B coalesced per quarter-wave
    {
        const int rw = t >> 5;
        const int q = t & 31;
        const size_t grow = (size_t)(rc0 + rw) * D_LEN;
        #pragma unroll
        for (int jl = 0; jl < 24; ++jl) {
            const int n = q + 32 * jl;
            const float2 v = unpack_bf2(Yu[grow + n]);
            const int pos = (n % 3) * 256 + n / 3;
            const int fi = 8 * pos + 2 * (pos >> 2) + rw;
            sre[fi] = v.x;
            sim[fi] = v.y;
        }
    }
    __syncthreads();

    // butterflies: m = t&3 row pair, q2 = t>>2 in 0..63
    const int m = t & 3;
    const int q2 = t >> 2;
    float2* s2re = (float2*)sre;
    float2* s2im = (float2*)sim;

#define BFLY4V(a0, a1, a2, a3, w1, w2, w3)                                      \
    {                                                                           \
        float2 ar = s2re[a0], ai = s2im[a0], br = s2re[a1], bi = s2im[a1];      \
        float2 cr = s2re[a2], ci = s2im[a2], er = s2re[a3], ei = s2im[a3];      \
        float2 t0r = make_float2(ar.x + cr.x, ar.y + cr.y);                     \
        float2 t0i = make_float2(ai.x + ci.x, ai.y + ci.y);                     \
        float2 t1r = make_float2(ar.x - cr.x, ar.y - cr.y);                     \
        float2 t1i = make_float2(ai.x - ci.x, ai.y - ci.y);                     \
        float2 t2r = make_float2(br.x + er.x, br.y + er.y);                     \
        float2 t2i = make_float2(bi.x + ei.x, bi.y + ei.y);                     \
        float2 t3r = make_float2(br.x - er.x, br.y - er.y);                     \
        float2 t3i = make_float2(bi.x - ei.x, bi.y - ei.y);                     \
        s2re[a0] = make_float2(t0r.x + t2r.x, t0r.y + t2r.y);                   \
        s2im[a0] = make_float2(t0i.x + t2i.x, t0i.y + t2i.y);                   \
        float2 B1r = make_float2(t1r.x + t3i.x, t1r.y + t3i.y);                 \
        float2 B1i = make_float2(t1i.x - t3r.x, t1i.y - t3r.y);                 \
        s2re[a1] = make_float2(B1r.x * w1.x - B1i.x * w1.y,                     \
                               B1r.y * w1.x - B1i.y * w1.y);                    \
        s2im[a1] = make_float2(B1r.x * w1.y + B1i.x * w1.x,                     \
                               B1r.y * w1.y + B1i.y * w1.x);                    \
        float2 B2r = make_float2(t0r.x - t2r.x, t0r.y - t2r.y);                 \
        float2 B2i = make_float2(t0i.x - t2i.x, t0i.y - t2i.y);                 \
        s2re[a2] = make_float2(B2r.x * w2.x - B2i.x * w2.y,                     \
                               B2r.y * w2.x - B2i.y * w2.y);                    \
        s2im[a2] = make_float2(B2r.x * w2.y + B2i.x * w2.x,                     \
                               B2r.y * w2.y + B2i.y * w2.x);                    \
        float2 B3r = make_float2(t1r.x - t3i.x, t1r.y - t3i.y);                 \
        float2 B3i = make_float2(t1i.x + t3r.x, t1i.y + t3r.y);                 \
        s2re[a3] = make_float2(B3r.x * w3.x - B3i.x * w3.y,                     \
                               B3r.y * w3.x - B3i.y * w3.y);                    \
        s2im[a3] = make_float2(B3r.x * w3.y + B3i.x * w3.x,                     \
                               B3r.y * w3.y + B3i.y * w3.x);                    \
    }
#define CSQ(w) make_float2((w).x * (w).x - (w).y * (w).y, 2.0f * (w).x * (w).y)
#define CMU(a, b) make_float2((a).x * (b).x - (a).y * (b).y,                    \
                              (a).x * (b).y + (a).y * (b).x)

    // stage L=256, Q=64
    #pragma unroll
    for (int jj = 0; jj < 3; ++jj) {
        const int bf = q2 + 64 * jj;
        const int sub = bf >> 6;
        const int p = bf & 63;
        const int base = sub * 256 + p;
        const float2 w1 = t768[3 * p];
        const float2 w2 = CSQ(w1);
        const float2 w3 = CMU(w1, w2);
        BFLY4V(F2(base) + m, F2(base + 64) + m, F2(base + 128) + m,
               F2(base + 192) + m, w1, w2, w3);
    }
    __syncthreads();
    // stage L=64, Q=16
    #pragma unroll
    for (int jj = 0; jj < 3; ++jj) {
        const int bf = q2 + 64 * jj;
        const int sub = bf >> 6;
        const int i = bf & 63;
        const int blk = i >> 4, p = i & 15;
        const int base = sub * 256 + blk * 64 + p;
        const float2 w1 = t768[12 * p];
        const float2 w2 = CSQ(w1);
        const float2 w3 = CMU(w1, w2);
        BFLY4V(F2(base) + m, F2(base + 16) + m, F2(base + 32) + m,
               F2(base + 48) + m, w1, w2, w3);
    }
    __syncthreads();
    // stage L=16, Q=4
    #pragma unroll
    for (int jj = 0; jj < 3; ++jj) {
        const int bf = q2 + 64 * jj;
        const int sub = bf >> 6;
        const int i = bf & 63;
        const int blk = i >> 2, p = i & 3;
        const int base = sub * 256 + blk * 16 + p;
        const float2 w1 = t768[48 * p];
        const float2 w2 = CSQ(w1);
        const float2 w3 = CMU(w1, w2);
        BFLY4V(F2(base) + m, F2(base + 4) + m, F2(base + 8) + m,
               F2(base + 12) + m, w1, w2, w3);
    }
    __syncthreads();
    // stage L=4, Q=1 (no twiddle)
    {
        const float2 wid = make_float2(1.0f, 0.0f);
        #pragma unroll
        for (int jj = 0; jj < 3; ++jj) {
            const int bf = q2 + 64 * jj;
            const int sub = bf >> 6;
            const int i = bf & 63;
            const int base = sub * 256 + 4 * i;
            BFLY4V(F2(base) + m, F2(base + 1) + m, F2(base + 2) + m,
                   F2(base + 3) + m, wid, wid, wid);
        }
    }
    __syncthreads();

    // decode 8 rows of this block
    size_t obase[8], mbase[8];
    bool domir[8];
    #pragma unroll
    for (int rr = 0; rr < 8; ++rr) {
        const int rc = rc0 + rr;
        const int bb = rc / ROWS_PB;
        const int qq = rc - bb * ROWS_PB;
        const int K1 = qq / NK2;
        const int K2 = qq - K1 * NK2;
        const int srow = 64 * K1 + K2;
        const size_t bs = (size_t)(b0 + bb) * S_LEN;
        obase[rr] = (bs + srow) * D_LEN;
        mbase[rr] = (bs + (S_LEN - srow)) * D_LEN;
        domir[rr] = (K2 >= 1 && K2 <= 31);
    }

    // combine (radix-3): thread handles bin kk = t for all 4 row pairs.
    const float W3r = -0.5f, W3i = -0.86602540378443864676f;
    const int kk = t;
    const int j8 = dr256(kk);
    const int e0 = F2(j8), e1 = F2(256 + j8), e2 = F2(512 + j8);
    const float2 w = t768[kk];
    const float c1 = w.x, s1 = w.y;
    const float c2 = c1 * c1 - s1 * s1, s2_ = 2.0f * c1 * s1;
    const int md0 = (kk == 0) ? 0 : (768 - kk);
    #pragma unroll
    for (int i2 = 0; i2 < 4; ++i2) {
        const float2 u0r = s2re[e0 + i2], u0i = s2im[e0 + i2];
        const float2 u1r = s2re[e1 + i2], u1i = s2im[e1 + i2];
        const float2 u2r = s2re[e2 + i2], u2i = s2im[e2 + i2];
        const float2 v1r = make_float2(u1r.x * c1 - u1i.x * s1, u1r.y * c1 - u1i.y * s1);
        const float2 v1i = make_float2(u1r.x * s1 + u1i.x * c1, u1r.y * s1 + u1i.y * c1);
        const float2 v2r = make_float2(u2r.x * c2 - u2i.x * s2_, u2r.y * c2 - u2i.y * s2_);
        const float2 v2i = make_float2(u2r.x * s2_ + u2i.x * c2, u2r.y * s2_ + u2i.y * c2);
        const float2 y0 = make_float2(u0r.x + v1r.x + v2r.x, u0r.y + v1r.y + v2r.y);
        const float2 y1 = make_float2(
            u0r.x + (v1r.x * W3r - v1i.x * W3i) + (v2r.x * W3r + v2i.x * W3i),
            u0r.y + (v1r.y * W3r - v1i.y * W3i) + (v2r.y * W3r + v2i.y * W3i));
        const float2 y2 = make_float2(
            u0r.x + (v1r.x * W3r + v1i.x * W3i) + (v2r.x * W3r - v2i.x * W3i),
            u0r.y + (v1r.y * W3r + v1i.y * W3i) + (v2r.y * W3r - v2i.y * W3i));
        #pragma unroll
        for (int h = 0; h < 2; ++h) {
            const int rr = 2 * i2 + h;
            const float v0 = h ? y0.y : y0.x;
            const float v1 = h ? y1.y : y1.x;
            const float v2 = h ? y2.y : y2.x;
            __builtin_nontemporal_store(v0, &out[obase[rr] + kk]);
            __builtin_nontemporal_store(v1, &out[obase[rr] + 256 + kk]);
            __builtin_nontemporal_store(v2, &out[obase[rr] + 512 + kk]);
            if (domir[rr]) {
                __builtin_nontemporal_store(v0, &out[mbase[rr] + md0]);
                __builtin_nontemporal_store(v1, &out[mbase[rr] + 512 - kk]);
                __builtin_nontemporal_store(v2, &out[mbase[rr] + 256 - kk]);
            }
        }
    }
#undef BFLY4V
#undef CSQ
#undef CMU
}

extern "C" void kernel_launch(void* const* d_in, const int* in_sizes, int n_in,
                              void* d_out, int out_size, void* d_ws, size_t ws_size,
                              hipStream_t stream) {
    const float* x = (const float*)d_in[0];
    float* out = (float*)d_out;
    unsigned* Yu = (unsigned*)d_ws;

    const size_t full_plane_bytes = (size_t)4 * ROWS_PB * D_LEN * sizeof(unsigned);
    const size_t half_plane_bytes = full_plane_bytes / 2;
    int nb;
    if (ws_size >= full_plane_bytes) nb = 4;        // single pass (~52 MB)
    else if (ws_size >= half_plane_bytes) nb = 2;   // two passes (~26 MB)
    else return;

    for (int b0 = 0; b0 < 4; b0 += nb) {
        fft_s1_kernel<<<dim3(nb * 128), dim3(1024), 0, stream>>>(x, Yu, b0);
        fft_s2_kernel<<<dim3(nb * NK2 * 24), dim3(256), 0, stream>>>(Yu);
        fft_d_kernel<<<dim3(nb * ROWS_PB / 8), dim3(256), 0, stream>>>(Yu, out, b0);
    }
}